// Round 16
// baseline (331.506 us; speedup 1.0000x reference)
//
#include <hip/hip_runtime.h>

typedef short bf16x8 __attribute__((ext_vector_type(8)));
typedef float f32x4 __attribute__((ext_vector_type(4)));

__device__ __forceinline__ unsigned short f2bf(float f) {
    unsigned u = __float_as_uint(f);
    unsigned r = (u + 0x7fffu + ((u >> 16) & 1u)) >> 16;
    return (unsigned short)r;
}
__device__ __forceinline__ float bf2f(unsigned short u) {
    return __uint_as_float(((unsigned)u) << 16);
}

// ---------------- prep: W transposes, x cvt, csr=-1 init, degree hist ----
// deg is zeroed by a preceding hipMemsetAsync (stream-ordered).
__global__ void k_prep(const float* __restrict__ W1, unsigned short* __restrict__ W1T,
                       const float* __restrict__ W2, unsigned short* __restrict__ W2T,
                       const float* __restrict__ W3, unsigned short* __restrict__ W3T,
                       const float* __restrict__ x, unsigned short* __restrict__ xb,
                       int* __restrict__ csr, int Mcap,
                       const int* __restrict__ ei, int E, int* __restrict__ deg,
                       int DIN, int HC, int DOUT, int N)
{
    int i = blockIdx.x * blockDim.x + threadIdx.x;
    int n1 = DIN * HC;
    int n2 = n1 + HC * HC;
    int n3 = n2 + HC * DOUT;
    int n4 = n3 + N * DIN;
    int n5 = n4 + Mcap;
    int n6 = n5 + E;
    if (i < n1) {
        int k = i / HC, n = i - k * HC;
        W1T[n * DIN + k] = f2bf(W1[i]);
    } else if (i < n2) {
        int j = i - n1;
        int k = j / HC, n = j - k * HC;
        W2T[n * HC + k] = f2bf(W2[j]);
    } else if (i < n3) {
        int j = i - n2;
        int k = j / DOUT, n = j - k * DOUT;
        W3T[n * HC + k] = f2bf(W3[j]);
    } else if (i < n4) {
        int j = i - n3;
        xb[j] = f2bf(x[j]);
    } else if (i < n5) {
        csr[i - n4] = -1;           // pad sentinel
    } else if (i < n6) {
        atomicAdd(&deg[ei[E + (i - n5)]], 1);
    }
}

// scan of (deg+1) rounded up to multiple of 4 (padded segments)
__global__ void k_scan(const int* __restrict__ deg, int* __restrict__ off,
                       int* __restrict__ cur, int N) {
    __shared__ int sums[1024];
    int t = threadIdx.x;
    int chunk = (N + 1023) >> 10;
    int lo = t * chunk;
    int hi = lo + chunk; if (hi > N) hi = N;
    if (lo > N) lo = N;
    int s = 0;
    for (int i = lo; i < hi; ++i) s += (deg[i] + 4) & ~3;
    sums[t] = s;
    __syncthreads();
    for (int dd = 1; dd < 1024; dd <<= 1) {
        int v = (t >= dd) ? sums[t - dd] : 0;
        __syncthreads();
        sums[t] += v;
        __syncthreads();
    }
    int run = sums[t] - s;  // exclusive prefix
    for (int i = lo; i < hi; ++i) { off[i] = run; cur[i] = run; run += (deg[i] + 4) & ~3; }
    if (t == 1023) off[N] = run;
}
__global__ void k_fill(const int* __restrict__ ei, int E, int N,
                       int* cur, int* __restrict__ csr, int* __restrict__ dstarr) {
    int i = blockIdx.x * blockDim.x + threadIdx.x;
    if (i < E) {
        int s = ei[i], d = ei[E + i];
        int pos = atomicAdd(&cur[d], 1);
        csr[pos] = s;
        dstarr[pos] = d;
    } else if (i < E + N) {
        int nn = i - E;
        int pos = atomicAdd(&cur[nn], 1);
        csr[pos] = nn;
        dstarr[pos] = nn;
    }
}

// ---------------- GEMM: D[M,Nc] = A[M,K] (bf16) @ BT[Nc,K]^T (bf16) ----
template <bool OUTBF>
__global__ __launch_bounds__(256) void k_gemm(
    const unsigned short* __restrict__ A, const unsigned short* __restrict__ BT,
    void* __restrict__ D, int M, int K, int Nc, int tiles_n)
{
    int wid = blockIdx.x * (blockDim.x >> 6) + (threadIdx.x >> 6);
    int tiles_m = (M + 63) >> 6;
    if (wid >= tiles_m * tiles_n) return;
    int lane = threadIdx.x & 63;
    int tm = wid / tiles_n, tn = wid - tm * tiles_n;
    int m0 = tm << 6, n0 = tn << 6;
    int r = lane & 15, q = lane >> 4;

    const unsigned short* Arow[4];
    const unsigned short* Brow[4];
#pragma unroll
    for (int i = 0; i < 4; ++i) {
        int row = m0 + 16 * i + r; row = row < M ? row : M - 1;
        Arow[i] = A + (size_t)row * K + q * 8;
        Brow[i] = BT + (size_t)(n0 + 16 * i + r) * K + q * 8;
    }

    f32x4 acc[4][4] = {};
    bf16x8 a[4], b[4], a2[4], b2[4];
#pragma unroll
    for (int i = 0; i < 4; ++i) {
        a[i] = *(const bf16x8*)(Arow[i]);
        b[i] = *(const bf16x8*)(Brow[i]);
    }
    for (int k0 = 0; k0 < K; k0 += 32) {
        int kn = k0 + 32;
        if (kn < K) {
#pragma unroll
            for (int i = 0; i < 4; ++i) {
                a2[i] = *(const bf16x8*)(Arow[i] + kn);
                b2[i] = *(const bf16x8*)(Brow[i] + kn);
            }
        }
#pragma unroll
        for (int i = 0; i < 4; ++i)
#pragma unroll
            for (int j = 0; j < 4; ++j)
                acc[i][j] = __builtin_amdgcn_mfma_f32_16x16x32_bf16(a[i], b[j], acc[i][j], 0, 0, 0);
        if (kn < K) {
#pragma unroll
            for (int i = 0; i < 4; ++i) { a[i] = a2[i]; b[i] = b2[i]; }
        }
    }
#pragma unroll
    for (int i = 0; i < 4; ++i) {
        int rowb = m0 + 16 * i + q * 4;
#pragma unroll
        for (int rr = 0; rr < 4; ++rr) {
            int row = rowb + rr;
            if (row < M) {
#pragma unroll
                for (int j = 0; j < 4; ++j) {
                    int col = n0 + 16 * j + r;
                    if (OUTBF)
                        ((unsigned short*)D)[(size_t)row * Nc + col] = f2bf(acc[i][j][rr]);
                    else
                        ((float*)D)[(size_t)row * Nc + col] = acc[i][j][rr];
                }
            }
        }
    }
}

// ---------------- attention logits per node: al_s, al_d (bf16 h) ----------
template <int HCt, int Ht>
__global__ __launch_bounds__(256) void k_al(
    const unsigned short* __restrict__ h, const float* __restrict__ asrc,
    const float* __restrict__ adst,
    float* __restrict__ als, float* __restrict__ ald, int N)
{
    int wid = blockIdx.x * (blockDim.x >> 6) + (threadIdx.x >> 6);
    if (wid >= N) return;
    int lane = threadIdx.x & 63;
    const int CH = HCt / 64;
    const int Gs = 64 / Ht;  // lanes per head
    float s = 0.f, d = 0.f;
    if constexpr (CH == 8) {
        const uint4* hr = (const uint4*)(h + (size_t)wid * HCt) + lane;
        uint4 hv = *hr;
        unsigned wds[4] = {hv.x, hv.y, hv.z, hv.w};
        const f32x4* as4 = (const f32x4*)(asrc + lane * 8);
        const f32x4* ad4 = (const f32x4*)(adst + lane * 8);
        f32x4 av0 = as4[0], av1 = as4[1], dv0 = ad4[0], dv1 = ad4[1];
        float hf[8];
#pragma unroll
        for (int wv = 0; wv < 4; ++wv) {
            hf[2 * wv]     = __uint_as_float(wds[wv] << 16);
            hf[2 * wv + 1] = __uint_as_float(wds[wv] & 0xffff0000u);
        }
#pragma unroll
        for (int j = 0; j < 4; ++j) {
            s += hf[j] * av0[j] + hf[4 + j] * av1[j];
            d += hf[j] * dv0[j] + hf[4 + j] * dv1[j];
        }
    } else {
        // CH == 1 (layer 3): one bf16 per lane
        float hv = bf2f(h[(size_t)wid * HCt + lane]);
        s = hv * asrc[lane];
        d = hv * adst[lane];
    }
#pragma unroll
    for (int dd = 1; dd < Gs; dd <<= 1) {
        s += __shfl_xor(s, dd);
        d += __shfl_xor(d, dd);
    }
    if ((lane & (Gs - 1)) == 0) {
        int hh = lane / Gs;
        als[wid * Ht + hh] = s;
        ald[wid * Ht + hh] = d;
    }
}

// ---------------- edge alpha, SoA head planes: alpha[h*Mcap + t] ----------
// pads (csr<0) get alpha=0 so aggr needs no bounds/tail logic
__global__ void k_alpha4(const float* __restrict__ als, const float* __restrict__ ald,
                         const int* __restrict__ csr, const int* __restrict__ dstarr,
                         const int* __restrict__ off, int N,
                         float* __restrict__ alpha, int Mcap)
{
    int t = blockIdx.x * blockDim.x + threadIdx.x;
    if (t >= off[N]) return;
    int s = csr[t];
    if (s < 0) {
#pragma unroll
        for (int h = 0; h < 4; ++h) alpha[(size_t)h * Mcap + t] = 0.f;
        return;
    }
    int d = dstarr[t];
    f32x4 a = *(const f32x4*)(als + (size_t)s * 4);
    f32x4 b = *(const f32x4*)(ald + (size_t)d * 4);
#pragma unroll
    for (int h = 0; h < 4; ++h) {
        float l = a[h] + b[h];
        l = l > 0.f ? l : 0.2f * l;
        alpha[(size_t)h * Mcap + t] = __expf(l);
    }
}

// ---------------- aggr HC=512 H=4, quad-edge + depth-2 ping-pong ----------
// Wave = (node, head); 4 edge-groups x 16 lanes; each group consumes FOUR
// edges/iter (int4 csr + f32x4 alpha + 4x uint4 h). Segments padded to x4
// (alpha=0 on pads). Slab-sequential grid (head-major) keeps the h gather
// L2-resident per XCD. Ping-pong pipeline: quad q+4's loads issue before
// quad q's FMAs consume -> two gather chains in flight per wave.
template <bool DOELU>
__global__ __launch_bounds__(256) void k_aggr4b(
    const unsigned short* __restrict__ h, const float* __restrict__ alpha,
    const int* __restrict__ off, const int* __restrict__ csr,
    const float* __restrict__ bias,
    unsigned short* __restrict__ outp, int N, int nodeBlocks, int Mcap)
{
    int head = blockIdx.x / nodeBlocks;
    int nb = blockIdx.x - head * nodeBlocks;
    int n = nb * 4 + (threadIdx.x >> 6);
    if (n >= N) return;
    int lane = threadIdx.x & 63;
    int g = lane >> 4;            // edge group 0..3
    int p = lane & 15;            // channel-lane within group
    int q0 = (off[n] >> 2) + g, q1 = off[n + 1] >> 2;

    float acc[8] = {};
    float den = 0.f;
    const unsigned short* hbase = h + head * 128 + p * 8;
    const int4* csr4 = (const int4*)csr;
    const f32x4* al4 = (const f32x4*)(alpha + (size_t)head * Mcap);

    auto stage = [&](int q, f32x4& av, uint4* hq) {
        int4 cs = csr4[q];
        av = al4[q];
        int c0 = cs.x < 0 ? 0 : cs.x;   // pads: alpha=0, clamp address
        int c1 = cs.y < 0 ? 0 : cs.y;
        int c2 = cs.z < 0 ? 0 : cs.z;
        int c3 = cs.w < 0 ? 0 : cs.w;
        hq[0] = *(const uint4*)(hbase + ((size_t)(unsigned)c0 << 9));
        hq[1] = *(const uint4*)(hbase + ((size_t)(unsigned)c1 << 9));
        hq[2] = *(const uint4*)(hbase + ((size_t)(unsigned)c2 << 9));
        hq[3] = *(const uint4*)(hbase + ((size_t)(unsigned)c3 << 9));
    };
    auto consume = [&](const f32x4& av, const uint4* hq) {
        den += (av[0] + av[1]) + (av[2] + av[3]);
#pragma unroll
        for (int e = 0; e < 4; ++e) {
            float a = av[e];
            unsigned wds[4] = {hq[e].x, hq[e].y, hq[e].z, hq[e].w};
#pragma unroll
            for (int wv = 0; wv < 4; ++wv) {
                acc[2 * wv]     += a * __uint_as_float(wds[wv] << 16);
                acc[2 * wv + 1] += a * __uint_as_float(wds[wv] & 0xffff0000u);
            }
        }
    };

    int q = q0;
    if (q < q1) {
        f32x4 avA, avB; uint4 hqA[4], hqB[4];
        stage(q, avA, hqA);
        for (;;) {
            int qB = q + 4;
            bool hasB = qB < q1;
            if (hasB) stage(qB, avB, hqB);
            consume(avA, hqA);
            if (!hasB) break;
            int qA = qB + 4;
            bool hasA = qA < q1;
            if (hasA) stage(qA, avA, hqA);
            consume(avB, hqB);
            if (!hasA) break;
            q = qA;
        }
    }

    den += __shfl_xor(den, 16);
    den += __shfl_xor(den, 32);
#pragma unroll
    for (int j = 0; j < 8; ++j) {
        acc[j] += __shfl_xor(acc[j], 16);
        acc[j] += __shfl_xor(acc[j], 32);
    }

    if (g == 0) {
        float inv = 1.f / den;
        int cb = head * 128 + p * 8;
        unsigned ww[4];
#pragma unroll
        for (int wv = 0; wv < 4; ++wv) {
            float v0 = acc[2 * wv] * inv + bias[cb + 2 * wv];
            float v1 = acc[2 * wv + 1] * inv + bias[cb + 2 * wv + 1];
            if (DOELU) {
                v0 = v0 > 0.f ? v0 : expm1f(v0);
                v1 = v1 > 0.f ? v1 : expm1f(v1);
            }
            ww[wv] = (unsigned)f2bf(v0) | ((unsigned)f2bf(v1) << 16);
        }
        uint4 o; o.x = ww[0]; o.y = ww[1]; o.z = ww[2]; o.w = ww[3];
        *((uint4*)(outp + (size_t)n * 512 + cb)) = o;
    }
}

// ---------------- layer-3 aggr (HC=64, H=1, bf16 h), quad + ping-pong -----
__global__ __launch_bounds__(256) void k_aggr1b(
    const unsigned short* __restrict__ h, const float* __restrict__ als,
    const float* __restrict__ aldv, const int* __restrict__ off,
    const int* __restrict__ csr, const float* __restrict__ bias,
    float* __restrict__ outp, int N)
{
    int n = blockIdx.x * (blockDim.x >> 6) + (threadIdx.x >> 6);
    if (n >= N) return;
    int lane = threadIdx.x & 63;
    int g = lane >> 4;
    int p = lane & 15;
    int q0 = (off[n] >> 2) + g, q1 = off[n + 1] >> 2;
    float aldh = aldv[n];

    float acc[4] = {};
    float den = 0.f;
    const unsigned short* hbase = h + p * 4;   // lane owns 4 bf16 (8B)
    const int4* csr4 = (const int4*)csr;

    auto stage = [&](int q, f32x4& av, uint2* hq) {
        int4 cs = csr4[q];
        int c[4] = {cs.x, cs.y, cs.z, cs.w};
#pragma unroll
        for (int e = 0; e < 4; ++e) {
            int sc = c[e] < 0 ? 0 : c[e];
            float l = als[sc] + aldh;
            l = l > 0.f ? l : 0.2f * l;
            float ex = __expf(l);
            av[e] = c[e] < 0 ? 0.f : ex;
            hq[e] = *(const uint2*)(hbase + ((size_t)(unsigned)sc << 6));
        }
    };
    auto consume = [&](const f32x4& av, const uint2* hq) {
#pragma unroll
        for (int e = 0; e < 4; ++e) {
            float a = av[e];
            den += a;
            acc[0] += a * __uint_as_float(hq[e].x << 16);
            acc[1] += a * __uint_as_float(hq[e].x & 0xffff0000u);
            acc[2] += a * __uint_as_float(hq[e].y << 16);
            acc[3] += a * __uint_as_float(hq[e].y & 0xffff0000u);
        }
    };

    int q = q0;
    if (q < q1) {
        f32x4 avA, avB; uint2 hqA[4], hqB[4];
        stage(q, avA, hqA);
        for (;;) {
            int qB = q + 4;
            bool hasB = qB < q1;
            if (hasB) stage(qB, avB, hqB);
            consume(avA, hqA);
            if (!hasB) break;
            int qA = qB + 4;
            bool hasA = qA < q1;
            if (hasA) stage(qA, avA, hqA);
            consume(avB, hqB);
            if (!hasA) break;
            q = qA;
        }
    }

    den += __shfl_xor(den, 16);
    den += __shfl_xor(den, 32);
#pragma unroll
    for (int j = 0; j < 4; ++j) {
        acc[j] += __shfl_xor(acc[j], 16);
        acc[j] += __shfl_xor(acc[j], 32);
    }
    if (g == 0) {
        float inv = 1.f / den;
        f32x4 o;
#pragma unroll
        for (int j = 0; j < 4; ++j)
            o[j] = acc[j] * inv + bias[p * 4 + j];
        *((f32x4*)(outp + (size_t)n * 64 + p * 4)) = o;
    }
}

// --------------------------------------------------------------------------
extern "C" void kernel_launch(void* const* d_in, const int* in_sizes, int n_in,
                              void* d_out, int out_size, void* d_ws, size_t ws_size,
                              hipStream_t stream)
{
    const float* x   = (const float*)d_in[0];
    const int*   ei  = (const int*)d_in[1];
    const float* W1  = (const float*)d_in[2];
    const float* as1 = (const float*)d_in[3];
    const float* ad1 = (const float*)d_in[4];
    const float* b1  = (const float*)d_in[5];
    const float* W2  = (const float*)d_in[6];
    const float* as2 = (const float*)d_in[7];
    const float* ad2 = (const float*)d_in[8];
    const float* b2  = (const float*)d_in[9];
    const float* W3  = (const float*)d_in[10];
    const float* as3 = (const float*)d_in[11];
    const float* ad3 = (const float*)d_in[12];
    const float* b3  = (const float*)d_in[13];

    const int DIN = 256, HC = 512, DOUT = 64;
    int N = in_sizes[0] / DIN;
    int E = in_sizes[1] / 2;
    int Mcap = E + 4 * N;  // capacity for 4-padded CSR

    // workspace carve-up
    char* w = (char*)d_ws;
    auto alloc = [&](size_t bytes) -> char* {
        char* p = w;
        w += (bytes + 255) & ~(size_t)255;
        return p;
    };
    int* deg    = (int*)alloc((size_t)N * 4);
    int* cur    = (int*)alloc((size_t)N * 4);
    int* off    = (int*)alloc((size_t)(N + 1) * 4);
    int* csr    = (int*)alloc((size_t)Mcap * 4);
    int* dstarr = (int*)alloc((size_t)Mcap * 4);
    unsigned short* W1T = (unsigned short*)alloc((size_t)HC * DIN * 2);
    unsigned short* W2T = (unsigned short*)alloc((size_t)HC * HC * 2);
    unsigned short* W3T = (unsigned short*)alloc((size_t)DOUT * HC * 2);
    unsigned short* xb  = (unsigned short*)alloc((size_t)N * DIN * 2);
    unsigned short* act = (unsigned short*)alloc((size_t)N * HC * 2);
    unsigned short* hb  = (unsigned short*)alloc((size_t)N * HC * 2);
    unsigned short* hb3 = (unsigned short*)alloc((size_t)N * DOUT * 2);  // bf16 h (layer 3)
    float* als   = (float*)alloc((size_t)N * 4 * 4);
    float* ald   = (float*)alloc((size_t)N * 4 * 4);
    float* alpha = (float*)alloc((size_t)Mcap * 4 * 4);  // SoA: 4 planes of Mcap

    // ---- build: memset(deg) -> prep(+csr init+hist) -> scan -> fill ----
    hipMemsetAsync(deg, 0, (size_t)N * 4, stream);
    int prep_total = DIN * HC + HC * HC + HC * DOUT + N * DIN + Mcap + E;
    k_prep<<<(prep_total + 255) / 256, 256, 0, stream>>>(
        W1, W1T, W2, W2T, W3, W3T, x, xb, csr, Mcap, ei, E, deg, DIN, HC, DOUT, N);
    k_scan<<<1, 1024, 0, stream>>>(deg, off, cur, N);
    k_fill<<<(E + N + 255) / 256, 256, 0, stream>>>(ei, E, N, cur, csr, dstarr);

    int tiles_m = (N + 63) / 64;
    auto gemm_blocks = [&](int tn) { return (tiles_m * tn + 3) / 4; };
    int nwave_blocks = (N + 3) / 4;
    int nodeBlocks = (N + 3) / 4;
    int alpha_blocks = (Mcap + 255) / 256;

    // ---- layer 1 ----
    k_gemm<true><<<gemm_blocks(HC / 64), 256, 0, stream>>>(xb, W1T, hb, N, DIN, HC, HC / 64);
    k_al<512, 4><<<nwave_blocks, 256, 0, stream>>>(hb, as1, ad1, als, ald, N);
    k_alpha4<<<alpha_blocks, 256, 0, stream>>>(als, ald, csr, dstarr, off, N, alpha, Mcap);
    k_aggr4b<true><<<4 * nodeBlocks, 256, 0, stream>>>(hb, alpha, off, csr, b1, act, N, nodeBlocks, Mcap);

    // ---- layer 2 ----
    k_gemm<true><<<gemm_blocks(HC / 64), 256, 0, stream>>>(act, W2T, hb, N, HC, HC, HC / 64);
    k_al<512, 4><<<nwave_blocks, 256, 0, stream>>>(hb, as2, ad2, als, ald, N);
    k_alpha4<<<alpha_blocks, 256, 0, stream>>>(als, ald, csr, dstarr, off, N, alpha, Mcap);
    k_aggr4b<true><<<4 * nodeBlocks, 256, 0, stream>>>(hb, alpha, off, csr, b2, act, N, nodeBlocks, Mcap);

    // ---- layer 3 (bf16 h path) ----
    k_gemm<true><<<gemm_blocks(1), 256, 0, stream>>>(act, W3T, hb3, N, HC, DOUT, 1);
    k_al<64, 1><<<nwave_blocks, 256, 0, stream>>>(hb3, as3, ad3, als, ald, N);
    k_aggr1b<<<nwave_blocks, 256, 0, stream>>>(hb3, als, ald, off, csr, b3, (float*)d_out, N);
}

// Round 17
// 316.836 us; speedup vs baseline: 1.0463x; 1.0463x over previous
//
#include <hip/hip_runtime.h>

typedef short bf16x8 __attribute__((ext_vector_type(8)));
typedef float f32x4 __attribute__((ext_vector_type(4)));

__device__ __forceinline__ unsigned short f2bf(float f) {
    unsigned u = __float_as_uint(f);
    unsigned r = (u + 0x7fffu + ((u >> 16) & 1u)) >> 16;
    return (unsigned short)r;
}
__device__ __forceinline__ float bf2f(unsigned short u) {
    return __uint_as_float(((unsigned)u) << 16);
}

// ---------------- prep: W transposes, x cvt, csr=-1 init, degree hist ----
// deg is zeroed by a preceding hipMemsetAsync (stream-ordered).
__global__ void k_prep(const float* __restrict__ W1, unsigned short* __restrict__ W1T,
                       const float* __restrict__ W2, unsigned short* __restrict__ W2T,
                       const float* __restrict__ W3, unsigned short* __restrict__ W3T,
                       const float* __restrict__ x, unsigned short* __restrict__ xb,
                       int* __restrict__ csr, int Mcap,
                       const int* __restrict__ ei, int E, int* __restrict__ deg,
                       int DIN, int HC, int DOUT, int N)
{
    int i = blockIdx.x * blockDim.x + threadIdx.x;
    int n1 = DIN * HC;
    int n2 = n1 + HC * HC;
    int n3 = n2 + HC * DOUT;
    int n4 = n3 + N * DIN;
    int n5 = n4 + Mcap;
    int n6 = n5 + E;
    if (i < n1) {
        int k = i / HC, n = i - k * HC;
        W1T[n * DIN + k] = f2bf(W1[i]);
    } else if (i < n2) {
        int j = i - n1;
        int k = j / HC, n = j - k * HC;
        W2T[n * HC + k] = f2bf(W2[j]);
    } else if (i < n3) {
        int j = i - n2;
        int k = j / DOUT, n = j - k * DOUT;
        W3T[n * HC + k] = f2bf(W3[j]);
    } else if (i < n4) {
        int j = i - n3;
        xb[j] = f2bf(x[j]);
    } else if (i < n5) {
        csr[i - n4] = -1;           // pad sentinel
    } else if (i < n6) {
        atomicAdd(&deg[ei[E + (i - n5)]], 1);
    }
}

// scan of (deg+1) rounded up to multiple of 4 (padded segments)
__global__ void k_scan(const int* __restrict__ deg, int* __restrict__ off,
                       int* __restrict__ cur, int N) {
    __shared__ int sums[1024];
    int t = threadIdx.x;
    int chunk = (N + 1023) >> 10;
    int lo = t * chunk;
    int hi = lo + chunk; if (hi > N) hi = N;
    if (lo > N) lo = N;
    int s = 0;
    for (int i = lo; i < hi; ++i) s += (deg[i] + 4) & ~3;
    sums[t] = s;
    __syncthreads();
    for (int dd = 1; dd < 1024; dd <<= 1) {
        int v = (t >= dd) ? sums[t - dd] : 0;
        __syncthreads();
        sums[t] += v;
        __syncthreads();
    }
    int run = sums[t] - s;  // exclusive prefix
    for (int i = lo; i < hi; ++i) { off[i] = run; cur[i] = run; run += (deg[i] + 4) & ~3; }
    if (t == 1023) off[N] = run;
}
__global__ void k_fill(const int* __restrict__ ei, int E, int N,
                       int* cur, int* __restrict__ csr, int* __restrict__ dstarr) {
    int i = blockIdx.x * blockDim.x + threadIdx.x;
    if (i < E) {
        int s = ei[i], d = ei[E + i];
        int pos = atomicAdd(&cur[d], 1);
        csr[pos] = s;
        dstarr[pos] = d;
    } else if (i < E + N) {
        int nn = i - E;
        int pos = atomicAdd(&cur[nn], 1);
        csr[pos] = nn;
        dstarr[pos] = nn;
    }
}

// ---------------- GEMM: D[M,Nc] = A[M,K] (bf16) @ BT[Nc,K]^T (bf16) ----
template <bool OUTBF>
__global__ __launch_bounds__(256) void k_gemm(
    const unsigned short* __restrict__ A, const unsigned short* __restrict__ BT,
    void* __restrict__ D, int M, int K, int Nc, int tiles_n)
{
    int wid = blockIdx.x * (blockDim.x >> 6) + (threadIdx.x >> 6);
    int tiles_m = (M + 63) >> 6;
    if (wid >= tiles_m * tiles_n) return;
    int lane = threadIdx.x & 63;
    int tm = wid / tiles_n, tn = wid - tm * tiles_n;
    int m0 = tm << 6, n0 = tn << 6;
    int r = lane & 15, q = lane >> 4;

    const unsigned short* Arow[4];
    const unsigned short* Brow[4];
#pragma unroll
    for (int i = 0; i < 4; ++i) {
        int row = m0 + 16 * i + r; row = row < M ? row : M - 1;
        Arow[i] = A + (size_t)row * K + q * 8;
        Brow[i] = BT + (size_t)(n0 + 16 * i + r) * K + q * 8;
    }

    f32x4 acc[4][4] = {};
    bf16x8 a[4], b[4], a2[4], b2[4];
#pragma unroll
    for (int i = 0; i < 4; ++i) {
        a[i] = *(const bf16x8*)(Arow[i]);
        b[i] = *(const bf16x8*)(Brow[i]);
    }
    for (int k0 = 0; k0 < K; k0 += 32) {
        int kn = k0 + 32;
        if (kn < K) {
#pragma unroll
            for (int i = 0; i < 4; ++i) {
                a2[i] = *(const bf16x8*)(Arow[i] + kn);
                b2[i] = *(const bf16x8*)(Brow[i] + kn);
            }
        }
#pragma unroll
        for (int i = 0; i < 4; ++i)
#pragma unroll
            for (int j = 0; j < 4; ++j)
                acc[i][j] = __builtin_amdgcn_mfma_f32_16x16x32_bf16(a[i], b[j], acc[i][j], 0, 0, 0);
        if (kn < K) {
#pragma unroll
            for (int i = 0; i < 4; ++i) { a[i] = a2[i]; b[i] = b2[i]; }
        }
    }
#pragma unroll
    for (int i = 0; i < 4; ++i) {
        int rowb = m0 + 16 * i + q * 4;
#pragma unroll
        for (int rr = 0; rr < 4; ++rr) {
            int row = rowb + rr;
            if (row < M) {
#pragma unroll
                for (int j = 0; j < 4; ++j) {
                    int col = n0 + 16 * j + r;
                    if (OUTBF)
                        ((unsigned short*)D)[(size_t)row * Nc + col] = f2bf(acc[i][j][rr]);
                    else
                        ((float*)D)[(size_t)row * Nc + col] = acc[i][j][rr];
                }
            }
        }
    }
}

// ---------------- attention logits per node: al_s, al_d (bf16 h) ----------
template <int HCt, int Ht>
__global__ __launch_bounds__(256) void k_al(
    const unsigned short* __restrict__ h, const float* __restrict__ asrc,
    const float* __restrict__ adst,
    float* __restrict__ als, float* __restrict__ ald, int N)
{
    int wid = blockIdx.x * (blockDim.x >> 6) + (threadIdx.x >> 6);
    if (wid >= N) return;
    int lane = threadIdx.x & 63;
    const int CH = HCt / 64;
    const int Gs = 64 / Ht;  // lanes per head
    float s = 0.f, d = 0.f;
    if constexpr (CH == 8) {
        const uint4* hr = (const uint4*)(h + (size_t)wid * HCt) + lane;
        uint4 hv = *hr;
        unsigned wds[4] = {hv.x, hv.y, hv.z, hv.w};
        const f32x4* as4 = (const f32x4*)(asrc + lane * 8);
        const f32x4* ad4 = (const f32x4*)(adst + lane * 8);
        f32x4 av0 = as4[0], av1 = as4[1], dv0 = ad4[0], dv1 = ad4[1];
        float hf[8];
#pragma unroll
        for (int wv = 0; wv < 4; ++wv) {
            hf[2 * wv]     = __uint_as_float(wds[wv] << 16);
            hf[2 * wv + 1] = __uint_as_float(wds[wv] & 0xffff0000u);
        }
#pragma unroll
        for (int j = 0; j < 4; ++j) {
            s += hf[j] * av0[j] + hf[4 + j] * av1[j];
            d += hf[j] * dv0[j] + hf[4 + j] * dv1[j];
        }
    } else {
        // CH == 1 (layer 3): one bf16 per lane
        float hv = bf2f(h[(size_t)wid * HCt + lane]);
        s = hv * asrc[lane];
        d = hv * adst[lane];
    }
#pragma unroll
    for (int dd = 1; dd < Gs; dd <<= 1) {
        s += __shfl_xor(s, dd);
        d += __shfl_xor(d, dd);
    }
    if ((lane & (Gs - 1)) == 0) {
        int hh = lane / Gs;
        als[wid * Ht + hh] = s;
        ald[wid * Ht + hh] = d;
    }
}

// ---------------- edge alpha, SoA head planes: alpha[h*Mcap + t] ----------
// pads (csr<0) get alpha=0 so aggr needs no bounds/tail logic
__global__ void k_alpha4(const float* __restrict__ als, const float* __restrict__ ald,
                         const int* __restrict__ csr, const int* __restrict__ dstarr,
                         const int* __restrict__ off, int N,
                         float* __restrict__ alpha, int Mcap)
{
    int t = blockIdx.x * blockDim.x + threadIdx.x;
    if (t >= off[N]) return;
    int s = csr[t];
    if (s < 0) {
#pragma unroll
        for (int h = 0; h < 4; ++h) alpha[(size_t)h * Mcap + t] = 0.f;
        return;
    }
    int d = dstarr[t];
    f32x4 a = *(const f32x4*)(als + (size_t)s * 4);
    f32x4 b = *(const f32x4*)(ald + (size_t)d * 4);
#pragma unroll
    for (int h = 0; h < 4; ++h) {
        float l = a[h] + b[h];
        l = l > 0.f ? l : 0.2f * l;
        alpha[(size_t)h * Mcap + t] = __expf(l);
    }
}

// ---------------- aggr HC=512 H=4, quad-edge inner loop -------------------
// Wave = (node, head); 4 edge-groups x 16 lanes; each group consumes FOUR
// edges/iter: one int4 csr + one f32x4 alpha + 4x uint4 h rows. Segments are
// padded to x4 (alpha=0 on pads) -> no tail logic. Slab-sequential grid
// (head-major) keeps the h gather L2-resident per XCD.
// NOTE: no software pipeline — VGPR 16 / 8 waves per SIMD. Measured (r5,
// r8, r16): trading occupancy for per-wave ILP is net-negative here.
template <bool DOELU>
__global__ __launch_bounds__(256) void k_aggr4b(
    const unsigned short* __restrict__ h, const float* __restrict__ alpha,
    const int* __restrict__ off, const int* __restrict__ csr,
    const float* __restrict__ bias,
    unsigned short* __restrict__ outp, int N, int nodeBlocks, int Mcap)
{
    int head = blockIdx.x / nodeBlocks;
    int nb = blockIdx.x - head * nodeBlocks;
    int n = nb * 4 + (threadIdx.x >> 6);
    if (n >= N) return;
    int lane = threadIdx.x & 63;
    int g = lane >> 4;            // edge group 0..3
    int p = lane & 15;            // channel-lane within group
    int q0 = (off[n] >> 2) + g, q1 = off[n + 1] >> 2;

    float acc[8] = {};
    float den = 0.f;
    const unsigned short* hbase = h + head * 128 + p * 8;
    const int4* csr4 = (const int4*)csr;
    const f32x4* al4 = (const f32x4*)(alpha + (size_t)head * Mcap);

    auto fmaq = [&](float a, const uint4& hq) {
        unsigned wds[4] = {hq.x, hq.y, hq.z, hq.w};
#pragma unroll
        for (int wv = 0; wv < 4; ++wv) {
            acc[2 * wv]     += a * __uint_as_float(wds[wv] << 16);
            acc[2 * wv + 1] += a * __uint_as_float(wds[wv] & 0xffff0000u);
        }
    };

    for (int q = q0; q < q1; q += 4) {
        int4 cs = csr4[q];
        f32x4 av = al4[q];
        int c0 = cs.x < 0 ? 0 : cs.x;   // pads: alpha=0, clamp address
        int c1 = cs.y < 0 ? 0 : cs.y;
        int c2 = cs.z < 0 ? 0 : cs.z;
        int c3 = cs.w < 0 ? 0 : cs.w;
        uint4 h0 = *(const uint4*)(hbase + ((size_t)(unsigned)c0 << 9));
        uint4 h1 = *(const uint4*)(hbase + ((size_t)(unsigned)c1 << 9));
        uint4 h2 = *(const uint4*)(hbase + ((size_t)(unsigned)c2 << 9));
        uint4 h3 = *(const uint4*)(hbase + ((size_t)(unsigned)c3 << 9));
        den += (av[0] + av[1]) + (av[2] + av[3]);
        fmaq(av[0], h0);
        fmaq(av[1], h1);
        fmaq(av[2], h2);
        fmaq(av[3], h3);
    }

    den += __shfl_xor(den, 16);
    den += __shfl_xor(den, 32);
#pragma unroll
    for (int j = 0; j < 8; ++j) {
        acc[j] += __shfl_xor(acc[j], 16);
        acc[j] += __shfl_xor(acc[j], 32);
    }

    if (g == 0) {
        float inv = 1.f / den;
        int cb = head * 128 + p * 8;
        unsigned ww[4];
#pragma unroll
        for (int wv = 0; wv < 4; ++wv) {
            float v0 = acc[2 * wv] * inv + bias[cb + 2 * wv];
            float v1 = acc[2 * wv + 1] * inv + bias[cb + 2 * wv + 1];
            if (DOELU) {
                v0 = v0 > 0.f ? v0 : expm1f(v0);
                v1 = v1 > 0.f ? v1 : expm1f(v1);
            }
            ww[wv] = (unsigned)f2bf(v0) | ((unsigned)f2bf(v1) << 16);
        }
        uint4 o; o.x = ww[0]; o.y = ww[1]; o.z = ww[2]; o.w = ww[3];
        *((uint4*)(outp + (size_t)n * 512 + cb)) = o;
    }
}

// ---------------- layer-3 aggr (HC=64, H=1, bf16 h), quad-edge, inline exp
__global__ __launch_bounds__(256) void k_aggr1b(
    const unsigned short* __restrict__ h, const float* __restrict__ als,
    const float* __restrict__ aldv, const int* __restrict__ off,
    const int* __restrict__ csr, const float* __restrict__ bias,
    float* __restrict__ outp, int N)
{
    int n = blockIdx.x * (blockDim.x >> 6) + (threadIdx.x >> 6);
    if (n >= N) return;
    int lane = threadIdx.x & 63;
    int g = lane >> 4;
    int p = lane & 15;
    int q0 = (off[n] >> 2) + g, q1 = off[n + 1] >> 2;
    float aldh = aldv[n];

    float acc[4] = {};
    float den = 0.f;
    const unsigned short* hbase = h + p * 4;   // lane owns 4 bf16 (8B)
    const int4* csr4 = (const int4*)csr;

    auto aof = [&](int ss) -> float {
        int sc = ss < 0 ? 0 : ss;
        float l = als[sc] + aldh;
        l = l > 0.f ? l : 0.2f * l;
        float e = __expf(l);
        return ss < 0 ? 0.f : e;
    };
    auto fmaq = [&](float a, const uint2& hq) {
        den += a;
        acc[0] += a * __uint_as_float(hq.x << 16);
        acc[1] += a * __uint_as_float(hq.x & 0xffff0000u);
        acc[2] += a * __uint_as_float(hq.y << 16);
        acc[3] += a * __uint_as_float(hq.y & 0xffff0000u);
    };

    for (int q = q0; q < q1; q += 4) {
        int4 cs = csr4[q];
        float a0 = aof(cs.x), a1 = aof(cs.y), a2 = aof(cs.z), a3 = aof(cs.w);
        uint2 h0 = *(const uint2*)(hbase + ((size_t)(unsigned)(cs.x < 0 ? 0 : cs.x) << 6));
        uint2 h1 = *(const uint2*)(hbase + ((size_t)(unsigned)(cs.y < 0 ? 0 : cs.y) << 6));
        uint2 h2 = *(const uint2*)(hbase + ((size_t)(unsigned)(cs.z < 0 ? 0 : cs.z) << 6));
        uint2 h3 = *(const uint2*)(hbase + ((size_t)(unsigned)(cs.w < 0 ? 0 : cs.w) << 6));
        fmaq(a0, h0);
        fmaq(a1, h1);
        fmaq(a2, h2);
        fmaq(a3, h3);
    }

    den += __shfl_xor(den, 16);
    den += __shfl_xor(den, 32);
#pragma unroll
    for (int j = 0; j < 4; ++j) {
        acc[j] += __shfl_xor(acc[j], 16);
        acc[j] += __shfl_xor(acc[j], 32);
    }
    if (g == 0) {
        float inv = 1.f / den;
        f32x4 o;
#pragma unroll
        for (int j = 0; j < 4; ++j)
            o[j] = acc[j] * inv + bias[p * 4 + j];
        *((f32x4*)(outp + (size_t)n * 64 + p * 4)) = o;
    }
}

// --------------------------------------------------------------------------
extern "C" void kernel_launch(void* const* d_in, const int* in_sizes, int n_in,
                              void* d_out, int out_size, void* d_ws, size_t ws_size,
                              hipStream_t stream)
{
    const float* x   = (const float*)d_in[0];
    const int*   ei  = (const int*)d_in[1];
    const float* W1  = (const float*)d_in[2];
    const float* as1 = (const float*)d_in[3];
    const float* ad1 = (const float*)d_in[4];
    const float* b1  = (const float*)d_in[5];
    const float* W2  = (const float*)d_in[6];
    const float* as2 = (const float*)d_in[7];
    const float* ad2 = (const float*)d_in[8];
    const float* b2  = (const float*)d_in[9];
    const float* W3  = (const float*)d_in[10];
    const float* as3 = (const float*)d_in[11];
    const float* ad3 = (const float*)d_in[12];
    const float* b3  = (const float*)d_in[13];

    const int DIN = 256, HC = 512, DOUT = 64;
    int N = in_sizes[0] / DIN;
    int E = in_sizes[1] / 2;
    int Mcap = E + 4 * N;  // capacity for 4-padded CSR

    // workspace carve-up
    char* w = (char*)d_ws;
    auto alloc = [&](size_t bytes) -> char* {
        char* p = w;
        w += (bytes + 255) & ~(size_t)255;
        return p;
    };
    int* deg    = (int*)alloc((size_t)N * 4);
    int* cur    = (int*)alloc((size_t)N * 4);
    int* off    = (int*)alloc((size_t)(N + 1) * 4);
    int* csr    = (int*)alloc((size_t)Mcap * 4);
    int* dstarr = (int*)alloc((size_t)Mcap * 4);
    unsigned short* W1T = (unsigned short*)alloc((size_t)HC * DIN * 2);
    unsigned short* W2T = (unsigned short*)alloc((size_t)HC * HC * 2);
    unsigned short* W3T = (unsigned short*)alloc((size_t)DOUT * HC * 2);
    unsigned short* xb  = (unsigned short*)alloc((size_t)N * DIN * 2);
    unsigned short* act = (unsigned short*)alloc((size_t)N * HC * 2);
    unsigned short* hb  = (unsigned short*)alloc((size_t)N * HC * 2);
    unsigned short* hb3 = (unsigned short*)alloc((size_t)N * DOUT * 2);  // bf16 h (layer 3)
    float* als   = (float*)alloc((size_t)N * 4 * 4);
    float* ald   = (float*)alloc((size_t)N * 4 * 4);
    float* alpha = (float*)alloc((size_t)Mcap * 4 * 4);  // SoA: 4 planes of Mcap

    // ---- build: memset(deg) -> prep(+csr init+hist) -> scan -> fill ----
    hipMemsetAsync(deg, 0, (size_t)N * 4, stream);
    int prep_total = DIN * HC + HC * HC + HC * DOUT + N * DIN + Mcap + E;
    k_prep<<<(prep_total + 255) / 256, 256, 0, stream>>>(
        W1, W1T, W2, W2T, W3, W3T, x, xb, csr, Mcap, ei, E, deg, DIN, HC, DOUT, N);
    k_scan<<<1, 1024, 0, stream>>>(deg, off, cur, N);
    k_fill<<<(E + N + 255) / 256, 256, 0, stream>>>(ei, E, N, cur, csr, dstarr);

    int tiles_m = (N + 63) / 64;
    auto gemm_blocks = [&](int tn) { return (tiles_m * tn + 3) / 4; };
    int nwave_blocks = (N + 3) / 4;
    int nodeBlocks = (N + 3) / 4;
    int alpha_blocks = (Mcap + 255) / 256;

    // ---- layer 1 ----
    k_gemm<true><<<gemm_blocks(HC / 64), 256, 0, stream>>>(xb, W1T, hb, N, DIN, HC, HC / 64);
    k_al<512, 4><<<nwave_blocks, 256, 0, stream>>>(hb, as1, ad1, als, ald, N);
    k_alpha4<<<alpha_blocks, 256, 0, stream>>>(als, ald, csr, dstarr, off, N, alpha, Mcap);
    k_aggr4b<true><<<4 * nodeBlocks, 256, 0, stream>>>(hb, alpha, off, csr, b1, act, N, nodeBlocks, Mcap);

    // ---- layer 2 ----
    k_gemm<true><<<gemm_blocks(HC / 64), 256, 0, stream>>>(act, W2T, hb, N, HC, HC, HC / 64);
    k_al<512, 4><<<nwave_blocks, 256, 0, stream>>>(hb, as2, ad2, als, ald, N);
    k_alpha4<<<alpha_blocks, 256, 0, stream>>>(als, ald, csr, dstarr, off, N, alpha, Mcap);
    k_aggr4b<true><<<4 * nodeBlocks, 256, 0, stream>>>(hb, alpha, off, csr, b2, act, N, nodeBlocks, Mcap);

    // ---- layer 3 (bf16 h path) ----
    k_gemm<true><<<gemm_blocks(1), 256, 0, stream>>>(act, W3T, hb3, N, HC, DOUT, 1);
    k_al<64, 1><<<nwave_blocks, 256, 0, stream>>>(hb3, as3, ad3, als, ald, N);
    k_aggr1b<<<nwave_blocks, 256, 0, stream>>>(hb3, als, ald, off, csr, b3, (float*)d_out, N);
}